// Round 26
// baseline (35.590 us; speedup 1.0000x reference)
//
#include <hip/hip_runtime.h>
#include <hip/hip_fp16.h>

typedef _Float16 f16x8 __attribute__((ext_vector_type(8)));
typedef _Float16 f16x2 __attribute__((ext_vector_type(2)));
typedef float f32x4 __attribute__((ext_vector_type(4)));

namespace {
constexpr int K = 4096;
constexpr int N = 11008;
constexpr int NC = N / 8;            // 1376 packed words per K-row
constexpr int KSPLIT = 32;           // 128-deep K slices = exactly 1 quant group
constexpr int SLICE_K = K / KSPLIT;  // 128
constexpr int BXW = 128;             // word-cols per block -> 512B/row contiguous
constexpr int NBX = 11;              // ceil(1376/128); block 10 covers 96 wcols
constexpr int BK = 32;               // K rows per MFMA step
constexpr int NT = SLICE_K / BK;     // 4 steps
constexpr int QS2 = SLICE_K + 5;     // q LDS col stride, words (133)
constexpr int XSH2 = SLICE_K + 16;   // x LDS row stride, halfs (144)
constexpr int OUT_ELEMS = 32 * N;    // 352256
}

// sum 32 f16 K-slice partials + bias -> out (8 outputs per thread)
__global__ void reduce_kernel(const _Float16* __restrict__ partial,
                              const float* __restrict__ bias,
                              float* __restrict__ out) {
  const int idx = (blockIdx.x * 256 + threadIdx.x) * 8;   // 172 blocks exact
  const int n = idx % N;
  const float4 b0 = *reinterpret_cast<const float4*>(bias + n);
  const float4 b1 = *reinterpret_cast<const float4*>(bias + n + 4);
  float a[8] = {b0.x, b0.y, b0.z, b0.w, b1.x, b1.y, b1.z, b1.w};
#pragma unroll
  for (int s = 0; s < KSPLIT; ++s) {
    const f16x8 p = *reinterpret_cast<const f16x8*>(partial + (long)s * OUT_ELEMS + idx);
#pragma unroll
    for (int j = 0; j < 8; ++j) a[j] += (float)p[j];
  }
  float4 o0 = {a[0], a[1], a[2], a[3]}, o1 = {a[4], a[5], a[6], a[7]};
  *reinterpret_cast<float4*>(out + idx)     = o0;
  *reinterpret_cast<float4*>(out + idx + 4) = o1;
}

// 512B-contiguous-per-row q staging (4x r21's 128B): BXW=128 word-cols per
// block, one-shot staging of q (68KB) + x f32->f16 (9KB), ONE barrier,
// 4 MFMA steps with zero VMEM. 8 waves; each wave owns 8 n-tiles.
__global__ __launch_bounds__(512, 2) void awq_gemm_kernel(
    const int* __restrict__ qw, const int* __restrict__ qz,
    const float* __restrict__ sc, const float* __restrict__ x,
    _Float16* __restrict__ partial)
{
  __shared__ int lqs[BXW * QS2];        // q tile, col-major [word-col][k], 68KB
  __shared__ _Float16 lxh[32 * XSH2];   // x tile f16, [row][k], 9KB

  const int tid  = threadIdx.x;
  const int lane = tid & 63;
  const int wid  = tid >> 6;      // wave 0..7
  const int kq   = lane >> 4;     // 0..3
  const int c16  = lane & 15;

  const int bx = blockIdx.x, by = blockIdx.y;
  const int n0 = bx * (BXW * 8);  // 1024 output cols per block
  const int c0 = bx * BXW;

  // AWQ nibble shift for col (n&7): 4*AWQ_ORDER[n&7], order [0,4,1,5,2,6,3,7]
  const int j7 = c16 & 7;
  const int sh = ((j7 >> 1) | ((j7 & 1) << 2)) << 2;

  int ncol[8], cloc[8];
#pragma unroll
  for (int j = 0; j < 8; ++j) {
    ncol[j] = n0 + (wid * 8 + j) * 16 + c16;
    cloc[j] = (wid * 8 + j) * 2 + (c16 >> 3);   // local word-col 0..127
  }

  const int kbeg = by * SLICE_K;   // slice == quant group (SLICE_K == 128)

  // ---- q staging: 8 rounds; each row read as 512B contiguous by 32 lanes ----
  const int qrow = tid >> 5;       // 0..15 (k within round)
  const int qch  = tid & 31;       // int4 chunk within row
  const bool qok = (c0 + qch * 4 + 3) < NC;     // ragged block 10 guard
  const int4 z4 = {0, 0, 0, 0};

  int4 qv[4];
#pragma unroll
  for (int rr = 0; rr < 4; ++rr)
    qv[rr] = qok ? *reinterpret_cast<const int4*>(
        qw + (long)(kbeg + rr * 16 + qrow) * NC + c0 + qch * 4) : z4;

  // x: 8 f32 per thread, convert in flight
  const int xm = tid >> 4;         // 0..31
  const int xo = tid & 15;         // 0..15 (8-f32 chunk)
  const float* xrow = x + (long)xm * K + kbeg + xo * 8;
  const float4 xa = *reinterpret_cast<const float4*>(xrow);
  const float4 xb = *reinterpret_cast<const float4*>(xrow + 4);

  // group scalars (single group per slice), guarded for ragged block
  f16x2 s2[8], mz2[8];
#pragma unroll
  for (int j = 0; j < 8; ++j) {
    const bool ok = ncol[j] < N;
    const int zq = ok ? qz[by * NC + (ncol[j] >> 3)] : 0;
    const _Float16 s16 = ok ? (_Float16)sc[by * N + ncol[j]] : (_Float16)0.0f;
    const _Float16 mz  = (_Float16)(-(float)(1024 + ((zq >> sh) & 15)));
    s2[j][0] = s16; s2[j][1] = s16;
    mz2[j][0] = mz; mz2[j][1] = mz;
  }

  // write q rounds 0..3, then load+write rounds 4..7
#pragma unroll
  for (int rr = 0; rr < 4; ++rr) {
    const int k = rr * 16 + qrow;
    lqs[(qch * 4 + 0) * QS2 + k] = qv[rr].x;
    lqs[(qch * 4 + 1) * QS2 + k] = qv[rr].y;
    lqs[(qch * 4 + 2) * QS2 + k] = qv[rr].z;
    lqs[(qch * 4 + 3) * QS2 + k] = qv[rr].w;
  }
#pragma unroll
  for (int rr = 4; rr < 8; ++rr) {
    const int4 v = qok ? *reinterpret_cast<const int4*>(
        qw + (long)(kbeg + rr * 16 + qrow) * NC + c0 + qch * 4) : z4;
    const int k = rr * 16 + qrow;
    lqs[(qch * 4 + 0) * QS2 + k] = v.x;
    lqs[(qch * 4 + 1) * QS2 + k] = v.y;
    lqs[(qch * 4 + 2) * QS2 + k] = v.z;
    lqs[(qch * 4 + 3) * QS2 + k] = v.w;
  }
  {
    union { f16x2 h2[4]; f16x8 h8; } u;
    u.h2[0] = __builtin_bit_cast(f16x2, __builtin_amdgcn_cvt_pkrtz(xa.x, xa.y));
    u.h2[1] = __builtin_bit_cast(f16x2, __builtin_amdgcn_cvt_pkrtz(xa.z, xa.w));
    u.h2[2] = __builtin_bit_cast(f16x2, __builtin_amdgcn_cvt_pkrtz(xb.x, xb.y));
    u.h2[3] = __builtin_bit_cast(f16x2, __builtin_amdgcn_cvt_pkrtz(xb.z, xb.w));
    *reinterpret_cast<f16x8*>(&lxh[xm * XSH2 + xo * 8]) = u.h8;
  }

  __syncthreads();               // the ONLY barrier

  f32x4 acc[2][8] = {};          // [m-tile][n-tile]

#pragma unroll
  for (int t = 0; t < NT; ++t) {
    const f16x8 a0 = *reinterpret_cast<const f16x8*>(&lxh[c16 * XSH2 + t * BK + kq * 8]);
    const f16x8 a1 = *reinterpret_cast<const f16x8*>(&lxh[(c16 + 16) * XSH2 + t * BK + kq * 8]);

#pragma unroll
    for (int j = 0; j < 8; ++j) {
      const int base = cloc[j] * QS2 + t * BK + kq * 8;
      f16x8 b;
#pragma unroll
      for (int half = 0; half < 2; ++half) {
        const int4 q4 = *reinterpret_cast<const int4*>(&lqs[base + 4 * half]);
        const unsigned v0 = __builtin_amdgcn_ubfe((unsigned)q4.x, sh, 4);
        const unsigned v1 = __builtin_amdgcn_ubfe((unsigned)q4.y, sh, 4);
        const unsigned v2 = __builtin_amdgcn_ubfe((unsigned)q4.z, sh, 4);
        const unsigned v3 = __builtin_amdgcn_ubfe((unsigned)q4.w, sh, 4);
        const f16x2 h01 = __builtin_bit_cast(f16x2, (v0 | (v1 << 16)) | 0x64006400u);
        const f16x2 h23 = __builtin_bit_cast(f16x2, (v2 | (v3 << 16)) | 0x64006400u);
        const f16x2 w01 = (h01 + mz2[j]) * s2[j];   // exact (v-z), 1 rounding
        const f16x2 w23 = (h23 + mz2[j]) * s2[j];
        b[4 * half]     = w01[0];
        b[4 * half + 1] = w01[1];
        b[4 * half + 2] = w23[0];
        b[4 * half + 3] = w23[1];
      }
      acc[0][j] = __builtin_amdgcn_mfma_f32_16x16x32_f16(a0, b, acc[0][j], 0, 0, 0);
      acc[1][j] = __builtin_amdgcn_mfma_f32_16x16x32_f16(a1, b, acc[1][j], 0, 0, 0);
    }
  }

  // ---- epilogue: f16 partials, plain stores (ragged-guarded) ----
  _Float16* pp = partial + (long)by * OUT_ELEMS;
#pragma unroll
  for (int mt = 0; mt < 2; ++mt)
#pragma unroll
    for (int j = 0; j < 8; ++j)
      if (ncol[j] < N)
#pragma unroll
        for (int i = 0; i < 4; ++i) {
          const int row = mt * 16 + kq * 4 + i;
          pp[row * N + ncol[j]] = (_Float16)acc[mt][j][i];
        }
}

extern "C" void kernel_launch(void* const* d_in, const int* in_sizes, int n_in,
                              void* d_out, int out_size, void* d_ws, size_t ws_size,
                              hipStream_t stream) {
  const float* x    = (const float*)d_in[0];
  const int* qw     = (const int*)d_in[1];
  const int* qz     = (const int*)d_in[2];
  const float* sc   = (const float*)d_in[3];   // fp16 values delivered as f32
  const float* bias = (const float*)d_in[4];   // fp16 values delivered as f32
  float* out        = (float*)d_out;

  _Float16* partial = (_Float16*)d_ws;         // 32 x 352256 f16 = 22.5 MB

  awq_gemm_kernel<<<dim3(NBX, KSPLIT), 512, 0, stream>>>(qw, qz, sc, x, partial);
  reduce_kernel<<<dim3(OUT_ELEMS / (256 * 8)), 256, 0, stream>>>(partial, bias, out);
}